// Round 7
// baseline (164.073 us; speedup 1.0000x reference)
//
#include <hip/hip_runtime.h>
#include <hip/hip_bf16.h>

#define BSZ   8
#define NQ    1000
#define DM    256
#define MROWS (BSZ*NQ)
#define TOPK  10
#define NBLK  500

typedef __attribute__((ext_vector_type(8))) short short8;
typedef __attribute__((ext_vector_type(4))) float f32x4;
typedef unsigned short u16;
typedef unsigned int   u32;

static __device__ __forceinline__ float b2f(u16 u) { return __uint_as_float(((u32)u) << 16); }
static __device__ __forceinline__ u16 f2b(float f) {
    __hip_bfloat16 h = __float2bfloat16(f);   // RNE
    return *(u16*)&h;
}
// monotonic order-preserving float<->uint encoding (for atomicMax-based fmax)
static __device__ __forceinline__ u32 encf(float f) {
    u32 u = __float_as_uint(f);
    return (u & 0x80000000u) ? ~u : (u | 0x80000000u);
}
static __device__ __forceinline__ float decf(u32 e) {
    u32 u = (e & 0x80000000u) ? (e ^ 0x80000000u) : ~e;
    return __uint_as_float(u);
}

// ---- 16x256x256 GEMM tile: A (LDS bf16) @ WT (global bf16 [n][k]) ----------
// B fragments (16B contiguous per lane) are read straight from global — no
// W staging, no inner barriers; L2 serves the 500-block reuse. Leading
// __syncthreads orders the A-tile writes.
// EPI: 0 relu->OutL  1 ->OutL  2 ->OutG bf16  3 final residual ->OutF f32
template<int EPI>
static __device__ __forceinline__ void gemm16(
    const u16 (*__restrict__ A)[264], const u16* __restrict__ WT,
    const float* __restrict__ bias, u16 (*__restrict__ OutL)[264],
    u16* __restrict__ OutG, float* __restrict__ OutF,
    const float* __restrict__ tgt, const float* __restrict__ seed,
    int r0, int t)
{
    const int lane = t & 63, wave = t >> 6;
    const int m = lane & 15, quad = lane >> 4;
    f32x4 acc[4];
    #pragma unroll
    for (int nt = 0; nt < 4; ++nt)
        #pragma unroll
        for (int i = 0; i < 4; ++i) acc[nt][i] = 0.f;
    __syncthreads();
    #pragma unroll
    for (int kc = 0; kc < 4; ++kc)
        #pragma unroll
        for (int ks = 0; ks < 2; ++ks) {
            const int k0 = kc*64 + ks*32 + quad*8;
            const short8 a = *(const short8*)&A[m][k0];
            #pragma unroll
            for (int nt = 0; nt < 4; ++nt) {
                const int n = wave*64 + nt*16 + m;
                const short8 b = *(const short8*)&WT[(size_t)n*DM + k0];
                acc[nt] = __builtin_amdgcn_mfma_f32_16x16x32_bf16(a, b, acc[nt], 0, 0, 0);
            }
        }
    // C/D: row = quad*4+reg, col = wave*64+nt*16+m  (verified R4/R5)
    #pragma unroll
    for (int nt = 0; nt < 4; ++nt) {
        const int n = wave*64 + nt*16 + m;
        const float bb = bias ? bias[n] : 0.f;
        #pragma unroll
        for (int reg = 0; reg < 4; ++reg) {
            const int rl = quad*4 + reg;
            float v = acc[nt][reg] + bb;
            if (EPI == 0) OutL[rl][n] = f2b(fmaxf(v, 0.f));
            if (EPI == 1) OutL[rl][n] = f2b(v);
            if (EPI == 2) OutG[(size_t)(r0+rl)*DM + n] = f2b(v);
            if (EPI == 3) {
                const int R = r0 + rl;
                OutF[(size_t)R*DM + n] = tgt[(size_t)R*DM + n]
                                       + fmaxf(v, 0.f) * (1.f - seed[R]);
            }
        }
    }
}

// ============ K1: weight prep (blocks 0..79 extra duty) + IoU/top-k ==========
// Grid 500; every block handles 16 rows (4 rows/wave, ballot compaction).
// IoU is exact f32 (contract off) — bit-exact vs the numpy reference on every
// >=0.5 comparison, so attn_mask and the discrete top-k are exact.
__global__ __launch_bounds__(256) void prep_iou_k(
    const float* __restrict__ boxes, const float* __restrict__ seed,
    const float* __restrict__ W1, const float* __restrict__ W2,
    const float* __restrict__ W3, const float* __restrict__ W4,
    const float* __restrict__ W5, u16* __restrict__ WT,
    float* __restrict__ attn, int* __restrict__ cnt,
    int* __restrict__ inc0, int* __restrict__ idxs)
{
#pragma clang fp contract(off)
    __shared__ float sv_s[4][NQ];
    __shared__ int   sj_s[4][NQ];
    const int t = threadIdx.x, bl = blockIdx.x;
    const int lane = t & 63, wave = t >> 6;

    if (bl < 80) {
        const int mm = bl >> 4;
        const int kb = (bl & 15) * 16;
        const float* W = (mm==0)?W1:(mm==1)?W2:(mm==2)?W3:(mm==3)?W4:W5;
        u16* D = WT + (size_t)mm * DM * DM;
        u16 tmp[16];
        #pragma unroll
        for (int kk = 0; kk < 16; ++kk)
            tmp[kk] = f2b(W[(size_t)(kb+kk)*DM + t]);     // coalesced read
        #pragma unroll
        for (int kk = 0; kk < 16; ++kk)
            D[(size_t)t*DM + kb + kk] = tmp[kk];          // 32B/thread
    }

    float* sv = sv_s[wave];
    int*   sj = sj_s[wave];
    for (int rr = 0; rr < 4; ++rr) {
        const int row = bl*16 + wave*4 + rr;      // b*NQ + i
        const int b   = row / NQ;
        const float4 bi = *(const float4*)(boxes + (size_t)row * 4);
        const float ix0 = bi.x - 0.5f*bi.z, iy0 = bi.y - 0.5f*bi.w;
        const float ix1 = bi.x + 0.5f*bi.z, iy1 = bi.y + 0.5f*bi.w;
        const float area_i = (ix1-ix0)*(iy1-iy0);
        const float neg_i  = 1.f - seed[row];
        float* arow = attn + (size_t)row * NQ;
        int count = 0;
        for (int c = 0; c < 16; ++c) {
            const int j = c*64 + lane;
            bool pred = false; float ov = 0.f;
            if (j < NQ) {
                const float4 bj = *(const float4*)(boxes + (size_t)(b*NQ + j) * 4);
                const float x0 = bj.x - 0.5f*bj.z, y0 = bj.y - 0.5f*bj.w;
                const float x1 = bj.x + 0.5f*bj.z, y1 = bj.y + 0.5f*bj.w;
                const float area_j = (x1-x0)*(y1-y0);
                const float ltx = fmaxf(ix0, x0), lty = fmaxf(iy0, y0);
                const float rbx = fminf(ix1, x1), rby = fminf(iy1, y1);
                const float wx = fmaxf(rbx-ltx, 0.f), wy = fmaxf(rby-lty, 0.f);
                const float inter = wx*wy;
                const float uni = (area_i + area_j) - inter;
                const float iou = inter / uni;
                arow[j] = (iou >= 0.5f) ? 1.0f : 0.0f;
                ov = (iou * seed[b*NQ + j]) * neg_i;   // exact: seed,neg in {0,1}
                pred = (ov >= 0.5f);
            }
            const unsigned long long mask = __ballot(pred);
            if (pred) {
                const int pos = count + __popcll(mask & ((1ull << lane) - 1ull));
                sv[pos] = ov; sj[pos] = j;
            }
            count += (int)__popcll(mask);
        }
        if (lane == 0) {
            const int n = count;
            inc0[row] = (n < TOPK) ? 1 : 0;
            if (n <= TOPK) {
                cnt[row] = n;
                for (int k = 0; k < n; ++k) idxs[row*TOPK + k] = b*NQ + sj[k];
            } else {
                // exact top-10 under (value desc, index asc) == stable argsort
                float bv[TOPK]; int bj[TOPK];
                #pragma unroll
                for (int k = 0; k < TOPK; ++k) { bv[k] = -1.f; bj[k] = 0x7fffffff; }
                for (int e = 0; e < n; ++e) {
                    const float v = sv[e]; const int j = sj[e];
                    int w = 0;
                    #pragma unroll
                    for (int k = 1; k < TOPK; ++k)
                        if (bv[k] < bv[w] || (bv[k] == bv[w] && bj[k] > bj[w])) w = k;
                    if (v > bv[w] || (v == bv[w] && j < bj[w])) { bv[w] = v; bj[w] = j; }
                }
                cnt[row] = TOPK;
                for (int k = 0; k < TOPK; ++k) idxs[row*TOPK + k] = b*NQ + bj[k];
            }
        }
    }
}

// ============ K2: fused MLP chain  tgt -> H -> Y -> LN -> P ==================
__global__ __launch_bounds__(256) void mlp_k(
    const float* __restrict__ tgt, const u16* __restrict__ WT,
    const float* __restrict__ b1, const float* __restrict__ b2,
    const float* __restrict__ g2, const float* __restrict__ be2,
    u16* __restrict__ P)
{
    __shared__ __align__(16) u16 bufA[16][264];
    __shared__ __align__(16) u16 bufB[16][264];
    const int t = threadIdx.x, r0 = blockIdx.x * 16;
    const int lane = t & 63, wave = t >> 6;
    const u16* W1T = WT;
    const u16* W2T = WT + (size_t)1*DM*DM;
    const u16* W3T = WT + (size_t)2*DM*DM;

    // stage tgt f32 -> bufA bf16 (thread t: row t>>4, 16 cols from (t&15)*16)
    {
        const int r = t >> 4, c0 = (t & 15) * 16;
        const float* src = &tgt[(size_t)(r0 + r)*DM + c0];
        u16 h[16];
        #pragma unroll
        for (int q = 0; q < 4; ++q) {
            const float4 f = *(const float4*)&src[q*4];
            h[q*4+0] = f2b(f.x); h[q*4+1] = f2b(f.y);
            h[q*4+2] = f2b(f.z); h[q*4+3] = f2b(f.w);
        }
        *(uint4*)&bufA[r][c0]     = *(uint4*)&h[0];
        *(uint4*)&bufA[r][c0 + 8] = *(uint4*)&h[8];
    }
    gemm16<0>(bufA, W1T, b1, bufB, nullptr, nullptr, nullptr, nullptr, r0, t); // H
    gemm16<1>(bufB, W2T, b2, bufA, nullptr, nullptr, nullptr, nullptr, r0, t); // Y
    __syncthreads();
    // LayerNorm rows in LDS (wave w owns rows 4w..4w+3)
    for (int rr = 0; rr < 4; ++rr) {
        const int row = wave*4 + rr;
        float x[4];
        #pragma unroll
        for (int i = 0; i < 4; ++i) x[i] = b2f(bufA[row][lane + 64*i]);
        float s = x[0]+x[1]+x[2]+x[3];
        float q = x[0]*x[0]+x[1]*x[1]+x[2]*x[2]+x[3]*x[3];
        #pragma unroll
        for (int off = 32; off; off >>= 1) {
            s += __shfl_down(s, off, 64);
            q += __shfl_down(q, off, 64);
        }
        s = __shfl(s, 0, 64); q = __shfl(q, 0, 64);
        const float mn  = s * (1.f/DM);
        const float vr  = q * (1.f/DM) - mn*mn;
        const float inv = rsqrtf(vr + 1e-5f);
        #pragma unroll
        for (int i = 0; i < 4; ++i) {
            const int c = lane + 64*i;
            bufA[row][c] = f2b((x[i]-mn)*inv*g2[c] + be2[c]);
        }
    }
    // gemm3's leading __syncthreads orders the LN writes
    gemm16<2>(bufA, W3T, nullptr, nullptr, P, nullptr, nullptr, nullptr, r0, t);
}

// ============ K3: pairs (MFMA + atomicMax fold) + final GEMM + residual ======
__global__ __launch_bounds__(256) void pairs_final_k(
    const u16* __restrict__ P, const u16* __restrict__ WT,
    const float* __restrict__ b3, const float* __restrict__ b4,
    const float* __restrict__ b5,
    const int* __restrict__ cnt, const int* __restrict__ inc0,
    const int* __restrict__ idxs,
    const float* __restrict__ tgt, const float* __restrict__ seed,
    float* __restrict__ out)
{
    __shared__ __align__(16) u16 U[16][264];
    __shared__ u32 cmU[16][264];
    __shared__ int pl_rl[176], pl_j[176];
    __shared__ int sInc[16];
    __shared__ int np;
    const int t = threadIdx.x, bl = blockIdx.x, r0 = bl * 16;
    const int lane = t & 63, wave = t >> 6;
    const int m = lane & 15, quad = lane >> 4;
    const u16* W4T = WT + (size_t)3*DM*DM;
    const u16* W5T = WT + (size_t)4*DM*DM;

    if (t == 0) np = 0;
    __syncthreads();
    if (t < 16) {
        const int r = r0 + t;
        int c = cnt[r];
        c = (c < 0) ? 0 : ((c > TOPK) ? TOPK : c);
        sInc[t] = inc0[r];
        const int base = atomicAdd(&np, c);
        for (int k = 0; k < c; ++k) {
            pl_rl[base + k] = t;
            int j = idxs[r*TOPK + k];
            j = (j < 0) ? 0 : ((j >= MROWS) ? MROWS-1 : j);
            pl_j[base + k] = j;
        }
    }
    __syncthreads();
    const int npairs = np;
    #pragma unroll
    for (int rl2 = 0; rl2 < 16; ++rl2)
        cmU[rl2][t] = sInc[rl2] ? 0x80000000u /*encf(0)*/ : encf(-3.402823466e38f);
    const float bb3 = b3[t];

    for (int pc = 0; pc*16 < npairs; ++pc) {
        // build U chunk (col t owned by thread t)
        #pragma unroll
        for (int pp = 0; pp < 16; ++pp) {
            const int pr = pc*16 + pp;
            u16 uv = 0;
            if (pr < npairs) {
                const int i = r0 + pl_rl[pr];
                const int j = pl_j[pr];
                uv = f2b(fmaxf(b2f(P[(size_t)i*DM + t]) - b2f(P[(size_t)j*DM + t]) + bb3, 0.f));
            }
            U[pp][t] = uv;
        }
        __syncthreads();   // U ready (also orders cmU init / prior folds)
        f32x4 acc[4];
        #pragma unroll
        for (int nt = 0; nt < 4; ++nt)
            #pragma unroll
            for (int i = 0; i < 4; ++i) acc[nt][i] = 0.f;
        #pragma unroll
        for (int kc = 0; kc < 4; ++kc)
            #pragma unroll
            for (int ks = 0; ks < 2; ++ks) {
                const int k0 = kc*64 + ks*32 + quad*8;
                const short8 a = *(const short8*)&U[m][k0];
                #pragma unroll
                for (int nt = 0; nt < 4; ++nt) {
                    const int n = wave*64 + nt*16 + m;
                    const short8 b = *(const short8*)&W4T[(size_t)n*DM + k0];
                    acc[nt] = __builtin_amdgcn_mfma_f32_16x16x32_bf16(a, b, acc[nt], 0, 0, 0);
                }
            }
        // fold D (row = quad*4+reg = pair slot, col = n) into running max
        #pragma unroll
        for (int nt = 0; nt < 4; ++nt) {
            const int n = wave*64 + nt*16 + m;
            const float bb4 = b4[n];
            #pragma unroll
            for (int reg = 0; reg < 4; ++reg) {
                const int pr = pc*16 + quad*4 + reg;
                if (pr < npairs) {
                    const int rl2 = pl_rl[pr];
                    atomicMax(&cmU[rl2][n], encf(acc[nt][reg] + bb4));
                }
            }
        }
        __syncthreads();   // folds done; U free for next chunk
    }
    // CMAX -> bf16 A-tile (col t owned); gemm16's leading sync orders it
    #pragma unroll
    for (int rl2 = 0; rl2 < 16; ++rl2)
        U[rl2][t] = f2b(decf(cmU[rl2][t]));
    gemm16<3>(U, W5T, b5, nullptr, nullptr, out, tgt, seed, r0, t);
}

extern "C" void kernel_launch(void* const* d_in, const int* in_sizes, int n_in,
                              void* d_out, int out_size, void* d_ws, size_t ws_size,
                              hipStream_t stream)
{
    (void)in_sizes; (void)n_in; (void)out_size; (void)ws_size;
    const float* tgt   = (const float*)d_in[0];
    const float* seed  = (const float*)d_in[1];
    const float* boxes = (const float*)d_in[2];
    const float* W1 = (const float*)d_in[3];
    const float* b1 = (const float*)d_in[4];
    const float* W2 = (const float*)d_in[5];
    const float* b2 = (const float*)d_in[6];
    const float* g2 = (const float*)d_in[7];
    const float* be2= (const float*)d_in[8];
    const float* W3 = (const float*)d_in[9];
    const float* b3 = (const float*)d_in[10];
    const float* W4 = (const float*)d_in[11];
    const float* b4 = (const float*)d_in[12];
    const float* W5 = (const float*)d_in[13];
    const float* b5 = (const float*)d_in[14];

    float* out_tgt  = (float*)d_out;                     // 8*1000*256 f32
    float* out_attn = out_tgt + (size_t)MROWS * DM;      // 8*1000*1000 f32

    // ws: WT (5 x 128KB bf16) | P (4MB bf16) | meta (~0.36MB)  ~= 5.1 MB
    u16* WT   = (u16*)d_ws;
    u16* P    = WT + (size_t)5*DM*DM;
    int* cnt  = (int*)(P + (size_t)MROWS*DM);
    int* inc0 = cnt + MROWS;
    int* idxs = inc0 + MROWS;

    prep_iou_k<<<NBLK, 256, 0, stream>>>(boxes, seed, W1, W2, W3, W4, W5,
                                         WT, out_attn, cnt, inc0, idxs);
    mlp_k<<<NBLK, 256, 0, stream>>>(tgt, WT, b1, b2, g2, be2, P);
    pairs_final_k<<<NBLK, 256, 0, stream>>>(P, WT, b3, b4, b5, cnt, inc0, idxs,
                                            tgt, seed, out_tgt);
}

// Round 8
// 140.929 us; speedup vs baseline: 1.1642x; 1.1642x over previous
//
#include <hip/hip_runtime.h>
#include <hip/hip_bf16.h>

#define BSZ   8
#define NQ    1000
#define DM    256
#define MROWS (BSZ*NQ)
#define TOPK  10

typedef __attribute__((ext_vector_type(8))) short short8;
typedef __attribute__((ext_vector_type(4))) float f32x4;
typedef unsigned short u16;
typedef unsigned int   u32;

static __device__ __forceinline__ float b2f(u16 u) { return __uint_as_float(((u32)u) << 16); }
static __device__ __forceinline__ u16 f2b(float f) {
    __hip_bfloat16 h = __float2bfloat16(f);   // RNE
    return *(u16*)&h;
}
// monotonic order-preserving float<->uint encoding (for atomicMax-based fmax)
static __device__ __forceinline__ u32 encf(float f) {
    u32 u = __float_as_uint(f);
    return (u & 0x80000000u) ? ~u : (u | 0x80000000u);
}
static __device__ __forceinline__ float decf(u32 e) {
    u32 u = (e & 0x80000000u) ? (e ^ 0x80000000u) : ~e;
    return __uint_as_float(u);
}

// ============ K1: weight prep (blocks 0..79) + IoU/top-k (blocks 80..8079) ===
// IoU path is exact f32 (contract off) — matches the numpy f32 reference
// bit-exactly on every >=0.5 comparison, so attn_mask and the discrete top-k
// selection are exact. (R5 structure: block-per-row, max TLP.)
__global__ __launch_bounds__(256) void prep_iou_k(
    const float* __restrict__ boxes, const float* __restrict__ seed,
    const float* __restrict__ W1, const float* __restrict__ W2,
    const float* __restrict__ W3, const float* __restrict__ W4,
    const float* __restrict__ W5, u16* __restrict__ WT,
    float* __restrict__ attn, int* __restrict__ cnt,
    int* __restrict__ inc0, int* __restrict__ idxs)
{
#pragma clang fp contract(off)
    if (blockIdx.x < 80) {
        const int m  = blockIdx.x >> 4;
        const int kb = (blockIdx.x & 15) * 16;
        const float* W = (m==0)?W1:(m==1)?W2:(m==2)?W3:(m==3)?W4:W5;
        u16* D = WT + (size_t)m * DM * DM;
        const int t = threadIdx.x;           // n
        u16 tmp[16];
        #pragma unroll
        for (int kk = 0; kk < 16; ++kk)
            tmp[kk] = f2b(W[(size_t)(kb+kk)*DM + t]);    // coalesced read
        #pragma unroll
        for (int kk = 0; kk < 16; ++kk)
            D[(size_t)t*DM + kb + kk] = tmp[kk];         // 32B contiguous/thread
        return;
    }

    __shared__ float sv[NQ];
    __shared__ int   sj[NQ];
    __shared__ int   scount;
    const int t   = threadIdx.x;
    const int row = blockIdx.x - 80;     // b*NQ + i
    const int b   = row / NQ;
    if (t == 0) scount = 0;

    const float* bi = boxes + (size_t)row * 4;
    const float icx = bi[0], icy = bi[1], iw = bi[2], ih = bi[3];
    const float ix0 = icx - 0.5f*iw, iy0 = icy - 0.5f*ih;
    const float ix1 = icx + 0.5f*iw, iy1 = icy + 0.5f*ih;
    const float area_i = (ix1-ix0)*(iy1-iy0);
    const float neg_i  = 1.f - seed[row];
    __syncthreads();

    float* arow = attn + (size_t)row * NQ;
    for (int j = t; j < NQ; j += 256) {
        const float* bj = boxes + (size_t)(b*NQ + j) * 4;
        const float cx = bj[0], cy = bj[1], w = bj[2], h = bj[3];
        const float x0 = cx - 0.5f*w, y0 = cy - 0.5f*h;
        const float x1 = cx + 0.5f*w, y1 = cy + 0.5f*h;
        const float area_j = (x1-x0)*(y1-y0);
        const float ltx = fmaxf(ix0, x0), lty = fmaxf(iy0, y0);
        const float rbx = fminf(ix1, x1), rby = fminf(iy1, y1);
        const float wx = fmaxf(rbx-ltx, 0.f), wy = fmaxf(rby-lty, 0.f);
        const float inter = wx*wy;
        const float uni = (area_i + area_j) - inter;
        const float iou = inter / uni;
        arow[j] = (iou >= 0.5f) ? 1.0f : 0.0f;
        const float ov = (iou * seed[b*NQ + j]) * neg_i;  // exact: seed,neg in {0,1}
        if (ov >= 0.5f) {
            const int p = atomicAdd(&scount, 1);
            if (p < NQ) { sv[p] = ov; sj[p] = j; }
        }
    }
    __syncthreads();

    if (t == 0) {
        const int n = scount;
        inc0[row] = (n < TOPK) ? 1 : 0;
        if (n <= TOPK) {
            cnt[row] = n;
            for (int k = 0; k < n; ++k) idxs[row*TOPK + k] = b*NQ + sj[k];
        } else {
            // exact top-10 under (value desc, index asc) == stable argsort
            float bv[TOPK]; int bj[TOPK];
            #pragma unroll
            for (int k = 0; k < TOPK; ++k) { bv[k] = -1.f; bj[k] = 0x7fffffff; }
            for (int e = 0; e < n; ++e) {
                const float v = sv[e]; const int j = sj[e];
                int w = 0;
                #pragma unroll
                for (int k = 1; k < TOPK; ++k)
                    if (bv[k] < bv[w] || (bv[k] == bv[w] && bj[k] > bj[w])) w = k;
                if (v > bv[w] || (v == bv[w] && j < bj[w])) { bv[w] = v; bj[w] = j; }
            }
            cnt[row] = TOPK;
            for (int k = 0; k < TOPK; ++k) idxs[row*TOPK + k] = b*NQ + bj[k];
        }
    }
}

// ============ shared 16x256x256 block-GEMM (MFMA 16x16x32 bf16) ==============
// A is a [16][264] bf16 LDS tile; WT is [n][k] bf16 global, streamed through
// W_lds in 64-K chunks (cooperative coalesced staging). Epilogue variants:
//   0: relu(acc+bias) -> OutL    1: acc+bias -> OutL
//   2: acc -> OutG (bf16 global) 3: final residual -> OutF (f32 global)
template<int EPI>
static __device__ __forceinline__ void block_gemm256(
    const u16 (*__restrict__ A)[264], const u16* __restrict__ WT,
    const float* __restrict__ bias, u16 (*__restrict__ OutL)[264],
    u16* __restrict__ OutG, float* __restrict__ OutF,
    const float* __restrict__ tgt, const float* __restrict__ seed,
    int r0, u16 (*__restrict__ W_lds)[72], int t)
{
    const int lane = t & 63, wave = t >> 6;
    const int m = lane & 15, quad = lane >> 4;
    f32x4 acc[4];
    #pragma unroll
    for (int nt = 0; nt < 4; ++nt)
        #pragma unroll
        for (int i = 0; i < 4; ++i) acc[nt][i] = 0.f;
    for (int kc = 0; kc < 4; ++kc) {
        __syncthreads();   // A ready / W_lds & prior-A free for reuse
        #pragma unroll
        for (int pass = 0; pass < 8; ++pass) {
            const int n = pass*32 + (t >> 3), ko = (t & 7) * 8;
            *(uint4*)&W_lds[n][ko] = *(const uint4*)&WT[(size_t)n*DM + kc*64 + ko];
        }
        __syncthreads();
        #pragma unroll
        for (int ks = 0; ks < 2; ++ks) {
            const short8 a = *(const short8*)&A[m][kc*64 + ks*32 + quad*8];
            #pragma unroll
            for (int nt = 0; nt < 4; ++nt) {
                const int n = wave*64 + nt*16 + m;
                const short8 b = *(const short8*)&W_lds[n][ks*32 + quad*8];
                acc[nt] = __builtin_amdgcn_mfma_f32_16x16x32_bf16(a, b, acc[nt], 0, 0, 0);
            }
        }
    }
    // C/D: row = quad*4+reg, col = wave*64+nt*16+m  (verified R4/R5)
    #pragma unroll
    for (int nt = 0; nt < 4; ++nt) {
        const int n = wave*64 + nt*16 + m;
        const float bb = bias ? bias[n] : 0.f;
        #pragma unroll
        for (int reg = 0; reg < 4; ++reg) {
            const int rl = quad*4 + reg;
            float v = acc[nt][reg] + bb;
            if (EPI == 0) OutL[rl][n] = f2b(fmaxf(v, 0.f));
            if (EPI == 1) OutL[rl][n] = f2b(v);
            if (EPI == 2) OutG[(size_t)(r0+rl)*DM + n] = f2b(v);
            if (EPI == 3) {
                const int R = r0 + rl;
                OutF[(size_t)R*DM + n] = tgt[(size_t)R*DM + n]
                                       + fmaxf(v, 0.f) * (1.f - seed[R]);
            }
        }
    }
}

// ============ K2: fused MLP chain  tgt -> H -> Y -> LN -> P ==================
__global__ __launch_bounds__(256) void mlp_k(
    const float* __restrict__ tgt, const u16* __restrict__ WT,
    const float* __restrict__ b1, const float* __restrict__ b2,
    const float* __restrict__ g2, const float* __restrict__ be2,
    u16* __restrict__ P)
{
    __shared__ __align__(16) u16 bufA[16][264];
    __shared__ __align__(16) u16 bufB[16][264];
    __shared__ __align__(16) u16 W_lds[256][72];
    const int t = threadIdx.x, r0 = blockIdx.x * 16;
    const int lane = t & 63, wave = t >> 6;

    // stage tgt f32 -> bufA bf16 (thread t: row t>>4, 16 cols from (t&15)*16)
    {
        const int r = t >> 4, c0 = (t & 15) * 16;
        const float* src = &tgt[(size_t)(r0 + r)*DM + c0];
        u16 h[16];
        #pragma unroll
        for (int q = 0; q < 4; ++q) {
            const float4 f = *(const float4*)&src[q*4];
            h[q*4+0] = f2b(f.x); h[q*4+1] = f2b(f.y);
            h[q*4+2] = f2b(f.z); h[q*4+3] = f2b(f.w);
        }
        *(uint4*)&bufA[r][c0]     = *(uint4*)&h[0];
        *(uint4*)&bufA[r][c0 + 8] = *(uint4*)&h[8];
    }
    const u16* W1T = WT;
    const u16* W2T = WT + (size_t)1*DM*DM;
    const u16* W3T = WT + (size_t)2*DM*DM;

    block_gemm256<0>(bufA, W1T, b1, bufB, nullptr, nullptr, nullptr, nullptr, r0, W_lds, t); // H
    block_gemm256<1>(bufB, W2T, b2, bufA, nullptr, nullptr, nullptr, nullptr, r0, W_lds, t); // Y
    __syncthreads();
    // LayerNorm rows in LDS: wave w handles rows 4w..4w+3
    for (int rr = 0; rr < 4; ++rr) {
        const int row = wave*4 + rr;
        float x[4];
        #pragma unroll
        for (int i = 0; i < 4; ++i) x[i] = b2f(bufA[row][lane + 64*i]);
        float s = x[0]+x[1]+x[2]+x[3];
        float q = x[0]*x[0]+x[1]*x[1]+x[2]*x[2]+x[3]*x[3];
        #pragma unroll
        for (int off = 32; off; off >>= 1) {
            s += __shfl_down(s, off, 64);
            q += __shfl_down(q, off, 64);
        }
        s = __shfl(s, 0, 64); q = __shfl(q, 0, 64);
        const float mn  = s * (1.f/DM);
        const float vr  = q * (1.f/DM) - mn*mn;
        const float inv = rsqrtf(vr + 1e-5f);
        #pragma unroll
        for (int i = 0; i < 4; ++i) {
            const int c = lane + 64*i;
            bufA[row][c] = f2b((x[i]-mn)*inv*g2[c] + be2[c]);
        }
    }
    // gemm3's leading __syncthreads covers the LN writes
    block_gemm256<2>(bufA, W3T, nullptr, nullptr, P, nullptr, nullptr, nullptr, r0, W_lds, t);
}

// ============ K3: pairs (MFMA + atomicMax fold) + final GEMM + residual ======
// Single change vs R5: D is folded into the running max straight from the
// accumulator registers via LDS atomicMax on monotonic-encoded floats —
// removes the 16x264-f32 D round-trip and 2 barriers per pair chunk.
__global__ __launch_bounds__(256) void pairs_final_k(
    const u16* __restrict__ P, const u16* __restrict__ WT,
    const float* __restrict__ b3, const float* __restrict__ b4,
    const float* __restrict__ b5,
    const int* __restrict__ cnt, const int* __restrict__ inc0,
    const int* __restrict__ idxs,
    const float* __restrict__ tgt, const float* __restrict__ seed,
    float* __restrict__ out)
{
    __shared__ __align__(16) u16 U[16][264];
    __shared__ __align__(16) u16 W_lds[256][72];
    __shared__ u32 cmU[16][264];
    __shared__ int pl_rl[176], pl_j[176];
    __shared__ int sInc[16];
    __shared__ int np;
    const int t = threadIdx.x, r0 = blockIdx.x * 16;
    const int lane = t & 63, wave = t >> 6;
    const int m = lane & 15, quad = lane >> 4;
    const u16* W4T = WT + (size_t)3*DM*DM;
    const u16* W5T = WT + (size_t)4*DM*DM;

    if (t == 0) np = 0;
    __syncthreads();
    if (t < 16) {
        const int r = r0 + t;
        int c = cnt[r];
        c = (c < 0) ? 0 : ((c > TOPK) ? TOPK : c);
        sInc[t] = inc0[r];
        const int base = atomicAdd(&np, c);
        for (int k = 0; k < c; ++k) {
            pl_rl[base + k] = t;
            int j = idxs[r*TOPK + k];
            j = (j < 0) ? 0 : ((j >= MROWS) ? MROWS-1 : j);
            pl_j[base + k] = j;
        }
    }
    __syncthreads();
    const int npairs = np;
    #pragma unroll
    for (int rl2 = 0; rl2 < 16; ++rl2)
        cmU[rl2][t] = sInc[rl2] ? 0x80000000u /*encf(0)*/ : encf(-3.402823466e38f);
    const float bb3 = b3[t];

    for (int pc = 0; pc*16 < npairs; ++pc) {
        // build U chunk (col t owned by thread t)
        #pragma unroll
        for (int pp = 0; pp < 16; ++pp) {
            const int pr = pc*16 + pp;
            u16 uv = 0;
            if (pr < npairs) {
                const int i = r0 + pl_rl[pr];
                const int j = pl_j[pr];
                uv = f2b(fmaxf(b2f(P[(size_t)i*DM + t]) - b2f(P[(size_t)j*DM + t]) + bb3, 0.f));
            }
            U[pp][t] = uv;
        }
        f32x4 acc[4];
        #pragma unroll
        for (int nt = 0; nt < 4; ++nt)
            #pragma unroll
            for (int i = 0; i < 4; ++i) acc[nt][i] = 0.f;
        for (int kc = 0; kc < 4; ++kc) {
            __syncthreads();   // U built & prior folds done / W_lds free
            #pragma unroll
            for (int pass = 0; pass < 8; ++pass) {
                const int n = pass*32 + (t >> 3), ko = (t & 7) * 8;
                *(uint4*)&W_lds[n][ko] = *(const uint4*)&W4T[(size_t)n*DM + kc*64 + ko];
            }
            __syncthreads();
            #pragma unroll
            for (int ks = 0; ks < 2; ++ks) {
                const short8 a = *(const short8*)&U[m][kc*64 + ks*32 + quad*8];
                #pragma unroll
                for (int nt = 0; nt < 4; ++nt) {
                    const int n = wave*64 + nt*16 + m;
                    const short8 b = *(const short8*)&W_lds[n][ks*32 + quad*8];
                    acc[nt] = __builtin_amdgcn_mfma_f32_16x16x32_bf16(a, b, acc[nt], 0, 0, 0);
                }
            }
        }
        // fold D (row = quad*4+reg = pair slot, col = n) from registers
        #pragma unroll
        for (int nt = 0; nt < 4; ++nt) {
            const int n = wave*64 + nt*16 + m;
            const float bb4 = b4[n];
            #pragma unroll
            for (int reg = 0; reg < 4; ++reg) {
                const int pr = pc*16 + quad*4 + reg;
                if (pr < npairs) {
                    const int rl2 = pl_rl[pr];
                    atomicMax(&cmU[rl2][n], encf(acc[nt][reg] + bb4));
                }
            }
        }
        // no barrier needed here: next U build touches only U (col-owned);
        // the next chunk's first __syncthreads orders folds vs W_lds reuse.
    }
    __syncthreads();   // all folds complete before cross-thread cmU reads
    // CMAX -> bf16 A-tile (col t owned); gemm's leading sync orders it
    #pragma unroll
    for (int rl2 = 0; rl2 < 16; ++rl2)
        U[rl2][t] = f2b(decf(cmU[rl2][t]));
    block_gemm256<3>(U, W5T, b5, nullptr, nullptr, out, tgt, seed, r0, W_lds, t);
}

extern "C" void kernel_launch(void* const* d_in, const int* in_sizes, int n_in,
                              void* d_out, int out_size, void* d_ws, size_t ws_size,
                              hipStream_t stream)
{
    (void)in_sizes; (void)n_in; (void)out_size; (void)ws_size;
    const float* tgt   = (const float*)d_in[0];
    const float* seed  = (const float*)d_in[1];
    const float* boxes = (const float*)d_in[2];
    const float* W1 = (const float*)d_in[3];
    const float* b1 = (const float*)d_in[4];
    const float* W2 = (const float*)d_in[5];
    const float* b2 = (const float*)d_in[6];
    const float* g2 = (const float*)d_in[7];
    const float* be2= (const float*)d_in[8];
    const float* W3 = (const float*)d_in[9];
    const float* b3 = (const float*)d_in[10];
    const float* W4 = (const float*)d_in[11];
    const float* b4 = (const float*)d_in[12];
    const float* W5 = (const float*)d_in[13];
    const float* b5 = (const float*)d_in[14];

    float* out_tgt  = (float*)d_out;                     // 8*1000*256 f32
    float* out_attn = out_tgt + (size_t)MROWS * DM;      // 8*1000*1000 f32

    // ws: WT (5 x 128KB bf16) | P (4MB bf16) | meta (~0.36MB)  ~= 5.1 MB
    u16* WT   = (u16*)d_ws;
    u16* P    = WT + (size_t)5*DM*DM;
    int* cnt  = (int*)(P + (size_t)MROWS*DM);
    int* inc0 = cnt + MROWS;
    int* idxs = inc0 + MROWS;

    prep_iou_k<<<80 + MROWS, 256, 0, stream>>>(boxes, seed, W1, W2, W3, W4, W5,
                                               WT, out_attn, cnt, inc0, idxs);
    mlp_k<<<MROWS/16, 256, 0, stream>>>(tgt, WT, b1, b2, g2, be2, P);
    pairs_final_k<<<MROWS/16, 256, 0, stream>>>(P, WT, b3, b4, b5, cnt, inc0, idxs,
                                                tgt, seed, out_tgt);
}